// Round 11
// baseline (1174.044 us; speedup 1.0000x reference)
//
#include <hip/hip_runtime.h>
#include <math.h>

#define NE 64
#define NTOK 16384
#define DD 4096
#define TOPK 2
#define BLOCK 1024            // 16 waves = 8 K-slices x 2 token-halves
#define TOKPB 64
#define KQN 8
#define KRANGE (DD / KQN)     // 512 k per wave
#define KC 16                 // k per chunk
#define NCH (KRANGE / KC)     // 32 chunks
#define LGSTR 68              // logit plane row stride (dwords)
#define LGPL (64 * LGSTR)     // 4352 dwords per plane
#define SMEM_DW (KQN * LGPL)  // 34816 dw = 139.3 KB; staging aliases [0,16384)

// Hybrid operand feed (R10-proven): x -> LDS DMA (T=4), w -> per-lane global
// float4 from L2 (E=8). R11 delta: 16 waves (4/SIMD at the same 128-VGPR
// budget) to hide the per-chunk w-load bubble R10 measured (occ 21%, 60%
// idle), + w-row base pointers hoisted so per-load offset is a 13-bit imm.

__device__ __forceinline__ void dma16(const float* g, float* l) {
  __builtin_amdgcn_global_load_lds(
      (const __attribute__((address_space(1))) void*)g,
      (__attribute__((address_space(3))) void*)l, 16, 0, 0);
}

__global__ __launch_bounds__(BLOCK) void router_kernel(
    const float* __restrict__ x, const float* __restrict__ gw,
    float* __restrict__ out, float* __restrict__ ws) {
  __shared__ __align__(16) float smem[SMEM_DW];

  const int tid = threadIdx.x;
  const int lane = tid & 63;
  const int wid = __builtin_amdgcn_readfirstlane(tid >> 6);
  const int kq = wid >> 1;  // K slice (KRANGE cols)
  const int h = wid & 1;    // token half (32 tokens)
  const int g = lane >> 3;  // expert sub-row: experts g + 8j
  const int s = lane & 7;   // token slot: tokens h*32 + s + 8t, t=0..3
  const int tok0 = blockIdx.x * TOKPB;

  // ---- x DMA source (per-lane, pre-swizzled; LDS dest wave-uniform+linear) --
  const int swz = (lane & 3) ^ ((lane >> 3) & 3);
  const float* pgx = x + (size_t)(tok0 + h * 32 + (lane >> 2)) * DD +
                     kq * KRANGE + swz * 4;
  const int sb = wid * 1024;  // staging dword base; buf b at +b*512

  // ---- w row pointers (hoisted once; per-load offset fits 13-bit imm) ----
  const float* wj0 = gw + (size_t)g * DD + kq * KRANGE;
  const float* wj1 = wj0 + (size_t)8 * DD;
  const float* wj2 = wj0 + (size_t)16 * DD;
  const float* wj3 = wj0 + (size_t)24 * DD;
  const float* wj4 = wj0 + (size_t)32 * DD;
  const float* wj5 = wj0 + (size_t)40 * DD;
  const float* wj6 = wj0 + (size_t)48 * DD;
  const float* wj7 = wj0 + (size_t)56 * DD;

  // ---- x LDS read byte bases per quad (conflict-free swizzle, R9/R10) ----
  const char* smb = (const char*)smem;
  int bxq[4];
#pragma unroll
  for (int Q = 0; Q < 4; ++Q)
    bxq[Q] = wid * 4096 + s * 64 + (((Q ^ (s >> 1)) & 3) << 4);

  float acc[4][8];
#pragma unroll
  for (int t = 0; t < 4; ++t)
#pragma unroll
    for (int j = 0; j < 8; ++j) acc[t][j] = 0.f;

#define ISSUE(B, C)                                                         \
  do {                                                                      \
    dma16(pgx + (size_t)(C) * KC, &smem[sb + (B) * 512]);                   \
    dma16(pgx + (size_t)16 * DD + (size_t)(C) * KC,                         \
          &smem[sb + (B) * 512 + 256]);                                     \
  } while (0)

#define WFMA(J, W)                                                          \
  do {                                                                      \
    acc[0][J] = fmaf(xv0.x, (W).x, acc[0][J]);                              \
    acc[0][J] = fmaf(xv0.y, (W).y, acc[0][J]);                              \
    acc[0][J] = fmaf(xv0.z, (W).z, acc[0][J]);                              \
    acc[0][J] = fmaf(xv0.w, (W).w, acc[0][J]);                              \
    acc[1][J] = fmaf(xv1.x, (W).x, acc[1][J]);                              \
    acc[1][J] = fmaf(xv1.y, (W).y, acc[1][J]);                              \
    acc[1][J] = fmaf(xv1.z, (W).z, acc[1][J]);                              \
    acc[1][J] = fmaf(xv1.w, (W).w, acc[1][J]);                              \
    acc[2][J] = fmaf(xv2.x, (W).x, acc[2][J]);                              \
    acc[2][J] = fmaf(xv2.y, (W).y, acc[2][J]);                              \
    acc[2][J] = fmaf(xv2.z, (W).z, acc[2][J]);                              \
    acc[2][J] = fmaf(xv2.w, (W).w, acc[2][J]);                              \
    acc[3][J] = fmaf(xv3.x, (W).x, acc[3][J]);                              \
    acc[3][J] = fmaf(xv3.y, (W).y, acc[3][J]);                              \
    acc[3][J] = fmaf(xv3.z, (W).z, acc[3][J]);                              \
    acc[3][J] = fmaf(xv3.w, (W).w, acc[3][J]);                              \
  } while (0)

#define QUADOP(B, Q, KO)                                                    \
  do {                                                                      \
    const float4 xv0 = *(const float4*)(smb + bxq[Q] + (B) * 2048 + 0);     \
    const float4 xv1 = *(const float4*)(smb + bxq[Q] + (B) * 2048 + 512);   \
    const float4 xv2 = *(const float4*)(smb + bxq[Q] + (B) * 2048 + 1024);  \
    const float4 xv3 = *(const float4*)(smb + bxq[Q] + (B) * 2048 + 1536);  \
    const float4 w0 = *(const float4*)(wj0 + (KO) + (Q)*4);                 \
    const float4 w1 = *(const float4*)(wj1 + (KO) + (Q)*4);                 \
    const float4 w2 = *(const float4*)(wj2 + (KO) + (Q)*4);                 \
    const float4 w3 = *(const float4*)(wj3 + (KO) + (Q)*4);                 \
    const float4 w4 = *(const float4*)(wj4 + (KO) + (Q)*4);                 \
    const float4 w5 = *(const float4*)(wj5 + (KO) + (Q)*4);                 \
    const float4 w6 = *(const float4*)(wj6 + (KO) + (Q)*4);                 \
    const float4 w7 = *(const float4*)(wj7 + (KO) + (Q)*4);                 \
    WFMA(0, w0);                                                            \
    WFMA(1, w1);                                                            \
    WFMA(2, w2);                                                            \
    WFMA(3, w3);                                                            \
    WFMA(4, w4);                                                            \
    WFMA(5, w5);                                                            \
    WFMA(6, w6);                                                            \
    WFMA(7, w7);                                                            \
  } while (0)

  ISSUE(0, 0);  // prologue: chunk 0 -> buf 0

  // main loop: wave-private pipeline (staging private -> no barriers);
  // vmcnt(2) = previous DMA pair done, just-issued pair stays in flight.
#pragma unroll 1
  for (int cc = 0; cc < NCH; cc += 2) {
    const int k0 = cc * KC;
    ISSUE(1, cc + 1);
    asm volatile("s_waitcnt vmcnt(2)" ::: "memory");
    QUADOP(0, 0, k0);
    QUADOP(0, 1, k0);
    QUADOP(0, 2, k0);
    QUADOP(0, 3, k0);
    if (cc + 2 < NCH) {
      ISSUE(0, cc + 2);
      asm volatile("s_waitcnt vmcnt(2)" ::: "memory");
    } else {
      asm volatile("s_waitcnt vmcnt(0)" ::: "memory");
    }
    QUADOP(1, 0, k0 + KC);
    QUADOP(1, 1, k0 + KC);
    QUADOP(1, 2, k0 + KC);
    QUADOP(1, 3, k0 + KC);
  }
#undef QUADOP
#undef WFMA
#undef ISSUE

  __syncthreads();  // staging dies; logit planes alias it

  // partial logits: plane[kq][tok 64][LGSTR]; row h*32+s+8t, col g+8j
  {
    float* pl = &smem[kq * LGPL];
#pragma unroll
    for (int t = 0; t < 4; ++t)
#pragma unroll
      for (int j = 0; j < 8; ++j)
        pl[(h * 32 + s + 8 * t) * LGSTR + g + 8 * j] = acc[t][j];
  }
  __syncthreads();

  // epilogue: wave wid -> tokens wid*4..+3; lane == expert
  float psum_local = 0.f, cnt_local = 0.f;
  float* out_v = out;                // (NTOK, 2) top-k vals
  float* out_i = out + NTOK * TOPK;  // (NTOK, 2) top-k idx as float
#pragma unroll 1
  for (int ii = 0; ii < 4; ++ii) {
    const int t = wid * 4 + ii;
    float v = 0.f;
#pragma unroll
    for (int p = 0; p < KQN; ++p) v += smem[p * LGPL + t * LGSTR + lane];
    float m = v;
#pragma unroll
    for (int sh = 32; sh > 0; sh >>= 1) m = fmaxf(m, __shfl_xor(m, sh, 64));
    float ex = expf(v - m);
    float ssum = ex;
#pragma unroll
    for (int sh = 32; sh > 0; sh >>= 1) ssum += __shfl_xor(ssum, sh, 64);
    float p = ex / ssum;
    psum_local += p;

    float v1 = p; int i1 = lane;  // top-1, ties -> lowest index
#pragma unroll
    for (int sh = 32; sh > 0; sh >>= 1) {
      float ov = __shfl_xor(v1, sh, 64);
      int oi = __shfl_xor(i1, sh, 64);
      if (ov > v1 || (ov == v1 && oi < i1)) { v1 = ov; i1 = oi; }
    }
    float v2 = (lane == i1) ? -INFINITY : p; int i2 = lane;  // top-2
#pragma unroll
    for (int sh = 32; sh > 0; sh >>= 1) {
      float ov = __shfl_xor(v2, sh, 64);
      int oi = __shfl_xor(i2, sh, 64);
      if (ov > v2 || (ov == v2 && oi < i2)) { v2 = ov; i2 = oi; }
    }
    cnt_local += (lane == i1 ? 1.f : 0.f) + (lane == i2 ? 1.f : 0.f);
    if (lane == 0) {
      const int tg = tok0 + t;
      out_v[tg * 2 + 0] = v1;
      out_v[tg * 2 + 1] = v2;
      out_i[tg * 2 + 0] = (float)i1;
      out_i[tg * 2 + 1] = (float)i2;
    }
  }
  // loss partials: ws[0:64] = pick counts, ws[64:128] = prob sums
  atomicAdd(ws + lane, cnt_local);
  atomicAdd(ws + NE + lane, psum_local);
}

__global__ void loss_kernel(const float* __restrict__ ws,
                            float* __restrict__ out) {
  const int lane = threadIdx.x & 63;
  float f = ws[lane] * (1.f / (float)(NTOK * TOPK));
  float p = ws[NE + lane] * (1.f / (float)NTOK);
  float v = f * p;  // loss = E * mean_i(f_i p_i) = sum_i f_i p_i
#pragma unroll
  for (int sh = 32; sh > 0; sh >>= 1) v += __shfl_xor(v, sh, 64);
  if (lane == 0) out[NTOK * TOPK * 2] = v;
}

extern "C" void kernel_launch(void* const* d_in, const int* in_sizes, int n_in,
                              void* d_out, int out_size, void* d_ws,
                              size_t ws_size, hipStream_t stream) {
  const float* x = (const float*)d_in[0];
  const float* gw = (const float*)d_in[1];
  float* out = (float*)d_out;
  float* ws = (float*)d_ws;

  hipMemsetAsync(d_ws, 0, 2 * NE * sizeof(float), stream);
  router_kernel<<<NTOK / TOKPB, BLOCK, 0, stream>>>(x, gw, out, ws);
  loss_kernel<<<1, 64, 0, stream>>>(ws, out);
}

// Round 12
// 245.823 us; speedup vs baseline: 4.7760x; 4.7760x over previous
//
#include <hip/hip_runtime.h>
#include <math.h>

#define NE 64
#define NTOK 16384
#define DD 4096
#define TOPK 2
#define BLOCK 512             // 8 waves = 8 K-slices
#define TOKPB 32              // half tile -> grid 512 = 2 blocks/CU (4 w/SIMD)
#define KQN 8
#define KRANGE (DD / KQN)     // 512 k per wave
#define KC 16                 // k per chunk
#define NCH (KRANGE / KC)     // 32 chunks
#define LGSTR 68              // logit plane row stride (dwords)
#define LGPL (TOKPB * LGSTR)  // 2176 dwords per plane
#define SMEM_DW (KQN * LGPL)  // 17408 dw = 69.6 KB; x staging aliases [0,8192)

// Hybrid operand feed (R10-proven, no spills / 0 conflicts / ideal fetch):
//   x -> LDS via global_load_lds DMA (T=4 tokens/lane)
//   w -> per-lane global float4 from L2 (E=8 experts/lane)
// R12 delta vs R10: TOKPB 64->32 so grid=512=2 blocks/CU -> 4 waves/SIMD at
// the allocator's fixed 128-VGPR (2wg/CU) budget -> R10's per-chunk latency
// bubbles (occ 21%, 60% idle) are covered by the extra resident waves.

__device__ __forceinline__ void dma16(const float* g, float* l) {
  __builtin_amdgcn_global_load_lds(
      (const __attribute__((address_space(1))) void*)g,
      (__attribute__((address_space(3))) void*)l, 16, 0, 0);
}

__global__ __launch_bounds__(BLOCK) void router_kernel(
    const float* __restrict__ x, const float* __restrict__ gw,
    float* __restrict__ out, float* __restrict__ ws) {
  __shared__ __align__(16) float smem[SMEM_DW];

  const int tid = threadIdx.x;
  const int lane = tid & 63;
  const int kq = __builtin_amdgcn_readfirstlane(tid >> 6);  // K slice
  const int g = lane >> 3;  // expert sub-row: experts g + 8j
  const int s = lane & 7;   // token slot: tokens s + 8t, t=0..3
  const int tok0 = blockIdx.x * TOKPB;

  // ---- x DMA source (per-lane, pre-swizzled; LDS dest wave-uniform+linear) --
  const int swz = (lane & 3) ^ ((lane >> 3) & 3);
  const float* pgx =
      x + (size_t)(tok0 + (lane >> 2)) * DD + kq * KRANGE + swz * 4;
  const int sb = kq * 1024;  // staging dword base; buf b at +b*512

  // ---- w row pointers (hoisted; per-load offset fits 13-bit imm) ----
  const float* wj0 = gw + (size_t)g * DD + kq * KRANGE;
  const float* wj1 = wj0 + (size_t)8 * DD;
  const float* wj2 = wj0 + (size_t)16 * DD;
  const float* wj3 = wj0 + (size_t)24 * DD;
  const float* wj4 = wj0 + (size_t)32 * DD;
  const float* wj5 = wj0 + (size_t)40 * DD;
  const float* wj6 = wj0 + (size_t)48 * DD;
  const float* wj7 = wj0 + (size_t)56 * DD;

  // ---- x LDS read byte bases per quad (conflict-free swizzle, R9/R10) ----
  const char* smb = (const char*)smem;
  int bxq[4];
#pragma unroll
  for (int Q = 0; Q < 4; ++Q)
    bxq[Q] = kq * 4096 + s * 64 + (((Q ^ (s >> 1)) & 3) << 4);

  float acc[4][8];
#pragma unroll
  for (int t = 0; t < 4; ++t)
#pragma unroll
    for (int j = 0; j < 8; ++j) acc[t][j] = 0.f;

#define ISSUE(B, C)                                                         \
  do {                                                                      \
    dma16(pgx + (size_t)(C) * KC, &smem[sb + (B) * 512]);                   \
    dma16(pgx + (size_t)16 * DD + (size_t)(C) * KC,                         \
          &smem[sb + (B) * 512 + 256]);                                     \
  } while (0)

#define WFMA(J, W)                                                          \
  do {                                                                      \
    acc[0][J] = fmaf(xv0.x, (W).x, acc[0][J]);                              \
    acc[0][J] = fmaf(xv0.y, (W).y, acc[0][J]);                              \
    acc[0][J] = fmaf(xv0.z, (W).z, acc[0][J]);                              \
    acc[0][J] = fmaf(xv0.w, (W).w, acc[0][J]);                              \
    acc[1][J] = fmaf(xv1.x, (W).x, acc[1][J]);                              \
    acc[1][J] = fmaf(xv1.y, (W).y, acc[1][J]);                              \
    acc[1][J] = fmaf(xv1.z, (W).z, acc[1][J]);                              \
    acc[1][J] = fmaf(xv1.w, (W).w, acc[1][J]);                              \
    acc[2][J] = fmaf(xv2.x, (W).x, acc[2][J]);                              \
    acc[2][J] = fmaf(xv2.y, (W).y, acc[2][J]);                              \
    acc[2][J] = fmaf(xv2.z, (W).z, acc[2][J]);                              \
    acc[2][J] = fmaf(xv2.w, (W).w, acc[2][J]);                              \
    acc[3][J] = fmaf(xv3.x, (W).x, acc[3][J]);                              \
    acc[3][J] = fmaf(xv3.y, (W).y, acc[3][J]);                              \
    acc[3][J] = fmaf(xv3.z, (W).z, acc[3][J]);                              \
    acc[3][J] = fmaf(xv3.w, (W).w, acc[3][J]);                              \
  } while (0)

#define QUADOP(B, Q, KO)                                                    \
  do {                                                                      \
    const float4 xv0 = *(const float4*)(smb + bxq[Q] + (B) * 2048 + 0);     \
    const float4 xv1 = *(const float4*)(smb + bxq[Q] + (B) * 2048 + 512);   \
    const float4 xv2 = *(const float4*)(smb + bxq[Q] + (B) * 2048 + 1024);  \
    const float4 xv3 = *(const float4*)(smb + bxq[Q] + (B) * 2048 + 1536);  \
    const float4 w0 = *(const float4*)(wj0 + (KO) + (Q)*4);                 \
    const float4 w1 = *(const float4*)(wj1 + (KO) + (Q)*4);                 \
    const float4 w2 = *(const float4*)(wj2 + (KO) + (Q)*4);                 \
    const float4 w3 = *(const float4*)(wj3 + (KO) + (Q)*4);                 \
    const float4 w4 = *(const float4*)(wj4 + (KO) + (Q)*4);                 \
    const float4 w5 = *(const float4*)(wj5 + (KO) + (Q)*4);                 \
    const float4 w6 = *(const float4*)(wj6 + (KO) + (Q)*4);                 \
    const float4 w7 = *(const float4*)(wj7 + (KO) + (Q)*4);                 \
    WFMA(0, w0);                                                            \
    WFMA(1, w1);                                                            \
    WFMA(2, w2);                                                            \
    WFMA(3, w3);                                                            \
    WFMA(4, w4);                                                            \
    WFMA(5, w5);                                                            \
    WFMA(6, w6);                                                            \
    WFMA(7, w7);                                                            \
  } while (0)

  ISSUE(0, 0);  // prologue: chunk 0 -> buf 0

  // main loop: wave-private pipeline (staging private -> no barriers);
  // vmcnt(2) = previous DMA pair done, just-issued pair stays in flight.
#pragma unroll 1
  for (int cc = 0; cc < NCH; cc += 2) {
    const int k0 = cc * KC;
    ISSUE(1, cc + 1);
    asm volatile("s_waitcnt vmcnt(2)" ::: "memory");
    QUADOP(0, 0, k0);
    QUADOP(0, 1, k0);
    QUADOP(0, 2, k0);
    QUADOP(0, 3, k0);
    if (cc + 2 < NCH) {
      ISSUE(0, cc + 2);
      asm volatile("s_waitcnt vmcnt(2)" ::: "memory");
    } else {
      asm volatile("s_waitcnt vmcnt(0)" ::: "memory");
    }
    QUADOP(1, 0, k0 + KC);
    QUADOP(1, 1, k0 + KC);
    QUADOP(1, 2, k0 + KC);
    QUADOP(1, 3, k0 + KC);
  }
#undef QUADOP
#undef WFMA
#undef ISSUE

  __syncthreads();  // staging dies; logit planes alias it

  // partial logits: plane[kq][tok 32][LGSTR]; row s+8t, col g+8j
  {
    float* pl = &smem[kq * LGPL];
#pragma unroll
    for (int t = 0; t < 4; ++t)
#pragma unroll
      for (int j = 0; j < 8; ++j)
        pl[(s + 8 * t) * LGSTR + g + 8 * j] = acc[t][j];
  }
  __syncthreads();

  // epilogue: wave kq -> tokens kq*4..+3; lane == expert
  float psum_local = 0.f, cnt_local = 0.f;
  float* out_v = out;                // (NTOK, 2) top-k vals
  float* out_i = out + NTOK * TOPK;  // (NTOK, 2) top-k idx as float
#pragma unroll 1
  for (int ii = 0; ii < 4; ++ii) {
    const int t = kq * 4 + ii;
    float v = 0.f;
#pragma unroll
    for (int p = 0; p < KQN; ++p) v += smem[p * LGPL + t * LGSTR + lane];
    float m = v;
#pragma unroll
    for (int sh = 32; sh > 0; sh >>= 1) m = fmaxf(m, __shfl_xor(m, sh, 64));
    float ex = expf(v - m);
    float ssum = ex;
#pragma unroll
    for (int sh = 32; sh > 0; sh >>= 1) ssum += __shfl_xor(ssum, sh, 64);
    float p = ex / ssum;
    psum_local += p;

    float v1 = p; int i1 = lane;  // top-1, ties -> lowest index
#pragma unroll
    for (int sh = 32; sh > 0; sh >>= 1) {
      float ov = __shfl_xor(v1, sh, 64);
      int oi = __shfl_xor(i1, sh, 64);
      if (ov > v1 || (ov == v1 && oi < i1)) { v1 = ov; i1 = oi; }
    }
    float v2 = (lane == i1) ? -INFINITY : p; int i2 = lane;  // top-2
#pragma unroll
    for (int sh = 32; sh > 0; sh >>= 1) {
      float ov = __shfl_xor(v2, sh, 64);
      int oi = __shfl_xor(i2, sh, 64);
      if (ov > v2 || (ov == v2 && oi < i2)) { v2 = ov; i2 = oi; }
    }
    cnt_local += (lane == i1 ? 1.f : 0.f) + (lane == i2 ? 1.f : 0.f);
    if (lane == 0) {
      const int tg = tok0 + t;
      out_v[tg * 2 + 0] = v1;
      out_v[tg * 2 + 1] = v2;
      out_i[tg * 2 + 0] = (float)i1;
      out_i[tg * 2 + 1] = (float)i2;
    }
  }
  // loss partials: ws[0:64] = pick counts, ws[64:128] = prob sums
  atomicAdd(ws + lane, cnt_local);
  atomicAdd(ws + NE + lane, psum_local);
}

__global__ void loss_kernel(const float* __restrict__ ws,
                            float* __restrict__ out) {
  const int lane = threadIdx.x & 63;
  float f = ws[lane] * (1.f / (float)(NTOK * TOPK));
  float p = ws[NE + lane] * (1.f / (float)NTOK);
  float v = f * p;  // loss = E * mean_i(f_i p_i) = sum_i f_i p_i
#pragma unroll
  for (int sh = 32; sh > 0; sh >>= 1) v += __shfl_xor(v, sh, 64);
  if (lane == 0) out[NTOK * TOPK * 2] = v;
}

extern "C" void kernel_launch(void* const* d_in, const int* in_sizes, int n_in,
                              void* d_out, int out_size, void* d_ws,
                              size_t ws_size, hipStream_t stream) {
  const float* x = (const float*)d_in[0];
  const float* gw = (const float*)d_in[1];
  float* out = (float*)d_out;
  float* ws = (float*)d_ws;

  hipMemsetAsync(d_ws, 0, 2 * NE * sizeof(float), stream);
  router_kernel<<<NTOK / TOKPB, BLOCK, 0, stream>>>(x, gw, out, ws);
  loss_kernel<<<1, 64, 0, stream>>>(ws, out);
}